// Round 5
// baseline (364.206 us; speedup 1.0000x reference)
//
#include <hip/hip_runtime.h>
#include <hip/hip_bf16.h>
#include <stdint.h>

#define TT 512
#define NB 128
#define EM 256
#define UN 256

typedef short bf16x8 __attribute__((ext_vector_type(8)));
typedef float floatx4 __attribute__((ext_vector_type(4)));
typedef _Float16 half8 __attribute__((ext_vector_type(8)));

__device__ inline unsigned short f2bf(float f) {
    union { float f; uint32_t u; } v; v.f = f;
    uint32_t r = v.u + 0x7fffu + ((v.u >> 16) & 1u);
    return (unsigned short)(r >> 16);
}
__device__ inline float bf2f(unsigned short b) {
    union { uint32_t u; float f; } v; v.u = ((uint32_t)b) << 16;
    return v.f;
}

// ---------------------------------------------------------------------------
// Kernel 1a: repack W (f32 [256 u][256 e]) -> MFMA B-frag order, bf16 (k_gemm)
// ---------------------------------------------------------------------------
__global__ void k_wfrag(const float* __restrict__ W, unsigned short* __restrict__ wfrag) {
    int idx = blockIdx.x * blockDim.x + threadIdx.x;  // 0..8191
    int lane = idx & 63;
    int tile = idx >> 6;            // kt*16 + nt
    int nt = tile & 15, kt = tile >> 4;
    int u  = nt * 16 + (lane & 15);
    int e0 = kt * 32 + (lane >> 4) * 8;
    unsigned short* dst = wfrag + (size_t)idx * 8;
    #pragma unroll
    for (int j = 0; j < 8; j++) dst[j] = f2bf(W[u * EM + e0 + j]);
}

// ---------------------------------------------------------------------------
// Kernel 1b: repack U (f32 [256 u][256 k]) -> MFMA B-frag order, f16 (k_rnn)
// ---------------------------------------------------------------------------
__global__ void k_ufrag(const float* __restrict__ U, _Float16* __restrict__ ufrag) {
    int idx = blockIdx.x * blockDim.x + threadIdx.x;  // 0..8191
    int lane = idx & 63;
    int tile = idx >> 6;
    int nt = tile & 15, kt = tile >> 4;
    int u  = nt * 16 + (lane & 15);
    int k0 = kt * 32 + (lane >> 4) * 8;
    _Float16* dst = ufrag + (size_t)idx * 8;
    #pragma unroll
    for (int j = 0; j < 8; j++) dst[j] = (_Float16)U[u * UN + k0 + j];
}

// ---------------------------------------------------------------------------
// Kernel 2: xw[b][t][u] = sum_e emb[sent[b][t]][e] * W[u][e], bf16 out.
// (unchanged from passing version)
// ---------------------------------------------------------------------------
__global__ __launch_bounds__(256, 2) void k_gemm(
    const int* __restrict__ sent, const float* __restrict__ emb,
    const unsigned short* __restrict__ wfrag, unsigned short* __restrict__ xw)
{
    int w    = threadIdx.x >> 6;
    int lane = threadIdx.x & 63;
    int m  = lane & 15;
    int kg = lane >> 4;
    int row = blockIdx.x * 64 + w * 16 + m;
    int tok = sent[row];
    const float* arow = emb + (size_t)tok * EM;

    bf16x8 a[8];
    #pragma unroll
    for (int kt = 0; kt < 8; kt++) {
        const float* p = arow + kt * 32 + kg * 8;
        float4 f0 = *(const float4*)p;
        float4 f1 = *(const float4*)(p + 4);
        bf16x8 t;
        t[0] = (short)f2bf(f0.x); t[1] = (short)f2bf(f0.y);
        t[2] = (short)f2bf(f0.z); t[3] = (short)f2bf(f0.w);
        t[4] = (short)f2bf(f1.x); t[5] = (short)f2bf(f1.y);
        t[6] = (short)f2bf(f1.z); t[7] = (short)f2bf(f1.w);
        a[kt] = t;
    }

    floatx4 acc[16];
    #pragma unroll
    for (int nt = 0; nt < 16; nt++) acc[nt] = floatx4{0.f, 0.f, 0.f, 0.f};

    #pragma unroll
    for (int kt = 0; kt < 8; kt++) {
        #pragma unroll
        for (int nt = 0; nt < 16; nt++) {
            bf16x8 bfr = *(const bf16x8*)(wfrag + ((size_t)(kt * 16 + nt) * 64 + lane) * 8);
            acc[nt] = __builtin_amdgcn_mfma_f32_16x16x32_bf16(a[kt], bfr, acc[nt], 0, 0, 0);
        }
    }

    int rbase = blockIdx.x * 64 + w * 16 + (lane >> 4) * 4;
    int cbase = lane & 15;
    #pragma unroll
    for (int nt = 0; nt < 16; nt++) {
        #pragma unroll
        for (int r = 0; r < 4; r++) {
            xw[(size_t)(rbase + r) * UN + nt * 16 + cbase] = f2bf(acc[nt][r]);
        }
    }
}

// ---------------------------------------------------------------------------
// Kernel 3 (v5): matrix-pipe RNN scan, 8-step-batched xw prefetch.
// 128 blocks x 256 threads; wave w owns N-tiles 4w..4w+3 (units 64w..64w+63).
// Per step: 8 broadcast ds_read_b128 A-frags, 32 MFMA as 4x(4 chains of 2),
// lane L selects acc for unit 64w+L = t, 1 tanh, 1 ds_write_b16, 1 barrier.
// xw global loads batched 8 steps ahead -> vmcnt drain at barriers amortized.
// ---------------------------------------------------------------------------
__global__ __launch_bounds__(256, 1) void k_rnn(
    const _Float16* __restrict__ ufrag, const unsigned short* __restrict__ xw,
    const float* __restrict__ W1, const float* __restrict__ b1,
    const float* __restrict__ W2, const float* __restrict__ b2,
    float* __restrict__ out)
{
    __shared__ __align__(16) _Float16 hb[2][256];
    __shared__ float hid[32];
    const int t    = threadIdx.x;
    const int lane = t & 63;
    const int w    = t >> 6;
    const int kg   = lane >> 4;
    const int b    = blockIdx.x;

    // U B-frags -> registers (loop-invariant): ufr[q][kt], tile nt = 4w+q
    half8 ufr[4][8];
    #pragma unroll
    for (int q = 0; q < 4; q++) {
        #pragma unroll
        for (int kt = 0; kt < 8; kt++) {
            ufr[q][kt] = *(const half8*)(ufrag + ((size_t)(kt * 16 + (4 * w + q)) * 64 + lane) * 8);
        }
    }

    hb[0][t] = (_Float16)0.f;
    hb[1][t] = (_Float16)0.f;
    __syncthreads();

    const unsigned short* xp = xw + (size_t)b * TT * UN + t;  // coalesced per wave

    unsigned short xs[8], xn[8];
    #pragma unroll
    for (int i = 0; i < 8; i++) xs[i] = xp[(size_t)i * UN];

    int cur = 0;
    const float c3 = -0.33333334f, c5 = 0.13333334f, c7 = -0.05396825f, c9 = 0.02186949f;
    const floatx4 zero4 = {0.f, 0.f, 0.f, 0.f};
    const int sel = lane >> 4;

    for (int s0 = 0; s0 < TT; s0 += 8) {
        // batch-issue next chunk's 8 xw loads (consumed next chunk; in flight
        // across this chunk's barriers, completing during the first step)
        int nb = (s0 + 8 < TT) ? s0 + 8 : TT - 8;
        #pragma unroll
        for (int i = 0; i < 8; i++) xn[i] = xp[(size_t)(nb + i) * UN];

        #pragma unroll
        for (int i = 0; i < 8; i++) {
            // A-frags: broadcast reads of h (conflict-free)
            half8 afr[8];
            const _Float16* hbase = hb[cur] + kg * 8;
            #pragma unroll
            for (int kt = 0; kt < 8; kt++) afr[kt] = *(const half8*)(hbase + kt * 32);

            // 4 independent 2-deep MFMA chains per N-tile
            float z[4];
            #pragma unroll
            for (int q = 0; q < 4; q++) {
                floatx4 c0 = zero4, c1 = zero4, c2 = zero4, c3v = zero4;
                c0  = __builtin_amdgcn_mfma_f32_16x16x32_f16(afr[0], ufr[q][0], c0, 0, 0, 0);
                c1  = __builtin_amdgcn_mfma_f32_16x16x32_f16(afr[1], ufr[q][1], c1, 0, 0, 0);
                c2  = __builtin_amdgcn_mfma_f32_16x16x32_f16(afr[2], ufr[q][2], c2, 0, 0, 0);
                c3v = __builtin_amdgcn_mfma_f32_16x16x32_f16(afr[3], ufr[q][3], c3v, 0, 0, 0);
                c0  = __builtin_amdgcn_mfma_f32_16x16x32_f16(afr[4], ufr[q][4], c0, 0, 0, 0);
                c1  = __builtin_amdgcn_mfma_f32_16x16x32_f16(afr[5], ufr[q][5], c1, 0, 0, 0);
                c2  = __builtin_amdgcn_mfma_f32_16x16x32_f16(afr[6], ufr[q][6], c2, 0, 0, 0);
                c3v = __builtin_amdgcn_mfma_f32_16x16x32_f16(afr[7], ufr[q][7], c3v, 0, 0, 0);
                z[q] = (c0[0] + c1[0]) + (c2[0] + c3v[0]);
            }

            float zz = (sel == 0) ? z[0] : (sel == 1) ? z[1] : (sel == 2) ? z[2] : z[3];
            zz += bf2f(xs[i]);

            float hn;
            if (__builtin_expect(fabsf(zz) > 0.75f, 0)) {
                float e = __expf(2.f * zz);
                hn = 1.f - 2.f * __builtin_amdgcn_rcpf(e + 1.f);
            } else {
                float x2f = zz * zz;
                float p = fmaf(x2f, c9, c7);
                p = fmaf(x2f, p, c5);
                p = fmaf(x2f, p, c3);
                hn = fmaf(zz * x2f, p, zz);
            }

            hb[cur ^ 1][t] = (_Float16)hn;
            __syncthreads();
            cur ^= 1;
        }

        #pragma unroll
        for (int i = 0; i < 8; i++) xs[i] = xn[i];
    }

    // ---- head: hidden = relu(h @ W1 + b1); logits; softmax
    if (t < 32) {
        float a = b1[t];
        for (int k = 0; k < 256; k++) a += (float)hb[cur][k] * W1[k * 32 + t];
        hid[t] = fmaxf(a, 0.f);
    }
    __syncthreads();
    if (t == 0) {
        float l0 = b2[0], l1 = b2[1];
        #pragma unroll
        for (int i = 0; i < 32; i++) {
            float hv = hid[i];
            l0 += hv * W2[2 * i];
            l1 += hv * W2[2 * i + 1];
        }
        float mx2 = fmaxf(l0, l1);
        float e0 = __expf(l0 - mx2), e1 = __expf(l1 - mx2);
        float inv = 1.f / (e0 + e1);
        out[2 * b]     = e0 * inv;
        out[2 * b + 1] = e1 * inv;
    }
}

extern "C" void kernel_launch(void* const* d_in, const int* in_sizes, int n_in,
                              void* d_out, int out_size, void* d_ws, size_t ws_size,
                              hipStream_t stream) {
    const int*   sent = (const int*)d_in[0];
    const float* emb  = (const float*)d_in[1];
    const float* W    = (const float*)d_in[2];
    const float* U    = (const float*)d_in[3];
    const float* W1   = (const float*)d_in[4];
    const float* b1   = (const float*)d_in[5];
    const float* W2   = (const float*)d_in[6];
    const float* b2   = (const float*)d_in[7];
    float* out = (float*)d_out;

    unsigned short* xw    = (unsigned short*)d_ws;                                        // 32 MB bf16 [B][T][U]
    unsigned short* wfrag = (unsigned short*)((char*)d_ws + (size_t)NB * TT * UN * 2);    // 128 KB
    _Float16*       ufrag = (_Float16*)((char*)d_ws + (size_t)NB * TT * UN * 2 + (size_t)UN * EM * 2); // 128 KB

    k_wfrag<<<32, 256, 0, stream>>>(W, wfrag);
    k_ufrag<<<32, 256, 0, stream>>>(U, ufrag);
    k_gemm<<<(NB * TT) / 64, 256, 0, stream>>>(sent, emb, wfrag, xw);
    k_rnn<<<NB, 256, 0, stream>>>(ufrag, xw, W1, b1, W2, b2, out);
}